// Round 12
// baseline (188.239 us; speedup 1.0000x reference)
//
#include <hip/hip_runtime.h>
#include <hip/hip_bf16.h>

#define IN_FEAT 128
#define N_HEADS 4
#define OUT_FEAT 32

typedef __attribute__((ext_vector_type(8))) short short8;
typedef __attribute__((ext_vector_type(4))) float floatx4;

// RNE float -> bf16 (hi) + bf16 residual (lo);  x ~= hi + lo  with ~2^-18 rel error
__device__ __forceinline__ void bf16split(float x, short& hi, short& lo) {
    unsigned u = __float_as_uint(x);
    unsigned r = (u + 0x7FFFu + ((u >> 16) & 1u)) & 0xFFFF0000u;
    hi = (short)(r >> 16);
    float res = x - __uint_as_float(r);
    unsigned u2 = __float_as_uint(res);
    unsigned r2 = u2 + 0x7FFFu + ((u2 >> 16) & 1u);
    lo = (short)(r2 >> 16);
}

__device__ __forceinline__ unsigned short bf16rne(float x) {
    unsigned u = __float_as_uint(x);
    return (unsigned short)((u + 0x7FFFu + ((u >> 16) & 1u)) >> 16);
}

// ---------------------------------------------------------------- wcomb (fragment-ordered bf16 hi/lo) + zero nd
// frag layout for mfma_f32_16x16x32_bf16 B-operand: lane l holds B[k][o] with
// o = t*16 + (l&15), k = kk*32 + (l>>4)*8 + j  ->  flat idx ((t*4+kk)*64 + l)*8 + j
__global__ void wcomb_kernel(const float* __restrict__ W_np, const float* __restrict__ W_fc,
                             const float* __restrict__ b_np,
                             short* __restrict__ WBh, short* __restrict__ WBl,
                             float* __restrict__ bvec,
                             float4* __restrict__ ndz, int zcnt) {
    // zero nd (N*8 floats = zcnt float4s), grid-stride
    for (int i = blockIdx.x * blockDim.x + threadIdx.x; i < zcnt; i += gridDim.x * blockDim.x)
        ndz[i] = (float4){0.f, 0.f, 0.f, 0.f};

    int i = blockIdx.x;      // 0..127 (k row of Wc)
    int o = threadIdx.x;     // 0..127 (output col)
    float acc = 0.0f;
    for (int j = 0; j < 128; j++) acc += W_np[i * 128 + j] * W_fc[j * 128 + o];
    short hi, lo;
    bf16split(acc, hi, lo);
    int t    = o >> 4;
    int kk   = i >> 5;
    int lane = ((i >> 3) & 3) * 16 + (o & 15);
    int jj   = i & 7;
    int fi = ((t * 4 + kk) * 64 + lane) * 8 + jj;
    WBh[fi] = hi;
    WBl[fi] = lo;
    if (i == 0) {
        float bb = 0.0f;
        for (int j = 0; j < 128; j++) bb += b_np[j] * W_fc[j * 128 + o];
        bvec[o] = bb;
    }
}

// ---------------------------------------------------------------- fused: edge MLP + 2-sector scatter  ||  node GEMM
// GEMM blocks are INTERLEAVED (one every S blocks) so scatter keeps the whole
// machine's atomic issue rate while GEMM rides idle MFMA slots (m114 co-schedule).
// GEMM: hbase = nf @ Wc + bvec; A plain bf16 (RNE), B split hi/lo -> 2 MFMAs.
__global__ __launch_bounds__(256) void fused_kernel(
        const float* __restrict__ ef,
        const int* __restrict__ src, const int* __restrict__ dst,
        const float* __restrict__ W1, const float* __restrict__ b1,
        const float* __restrict__ W2, const float* __restrict__ b2,
        float* __restrict__ nd, int* __restrict__ erank, int E,
        const float* __restrict__ nf,
        const short* __restrict__ WBh, const short* __restrict__ WBl,
        const float* __restrict__ bvec,
        float* __restrict__ hbase, int N, int gemmBlocks, int S) {
    int b = blockIdx.x;
    int q = b / S, r = b - q * S;
    if (r == 0 && q < gemmBlocks) {
        // ---------------- GEMM part (tile q: 64 nodes) ----------------
        const int w = threadIdx.x >> 6, l = threadIdx.x & 63;
        const int lrow = l & 15, lhalf = l >> 4;
        const int n0 = q * 64 + w * 16;
        const int arow = n0 + lrow;

        short8 ah[4];
#pragma unroll
        for (int kk = 0; kk < 4; kk++) {
            float v[8];
            if (arow < N) {
                const float* p = &nf[(size_t)arow * 128 + kk * 32 + lhalf * 8];
                float4 f0 = *(const float4*)p;
                float4 f1 = *(const float4*)(p + 4);
                v[0] = f0.x; v[1] = f0.y; v[2] = f0.z; v[3] = f0.w;
                v[4] = f1.x; v[5] = f1.y; v[6] = f1.z; v[7] = f1.w;
            } else {
#pragma unroll
                for (int j = 0; j < 8; j++) v[j] = 0.0f;
            }
#pragma unroll
            for (int j = 0; j < 8; j++) ah[kk][j] = (short)bf16rne(v[j]);
        }

        const short8* gbh = (const short8*)WBh;
        const short8* gbl = (const short8*)WBl;
        floatx4 acc[8];
#pragma unroll
        for (int t = 0; t < 8; t++) acc[t] = (floatx4){0.f, 0.f, 0.f, 0.f};
#pragma unroll
        for (int t = 0; t < 8; t++) {
#pragma unroll
            for (int kk = 0; kk < 4; kk++) {
                short8 bh = gbh[(t * 4 + kk) * 64 + l];
                short8 bl = gbl[(t * 4 + kk) * 64 + l];
                acc[t] = __builtin_amdgcn_mfma_f32_16x16x32_bf16(ah[kk], bh, acc[t], 0, 0, 0);
                acc[t] = __builtin_amdgcn_mfma_f32_16x16x32_bf16(ah[kk], bl, acc[t], 0, 0, 0);
            }
        }
        float bv[8];
#pragma unroll
        for (int t = 0; t < 8; t++) bv[t] = bvec[t * 16 + lrow];
#pragma unroll
        for (int r2 = 0; r2 < 4; r2++) {
            int node = n0 + lhalf * 4 + r2;
            if (node < N) {
#pragma unroll
                for (int t = 0; t < 8; t++)
                    hbase[(size_t)node * 128 + t * 16 + lrow] = acc[t][r2] + bv[t];
            }
        }
        return;
    }
    // ---------------- scatter part ----------------
    int nG = min(q + (r > 0 ? 1 : 0), gemmBlocks);   // # gemm blocks before b
    int t = (b - nG) * 256 + threadIdx.x;
    int e = t >> 3;
    int sub = t & 7;
    if (e >= E) return;
    float x0 = ef[e * 3 + 0], x1 = ef[e * 3 + 1], x2 = ef[e * 3 + 2];
    float hbuf[6];
#pragma unroll
    for (int j = 0; j < 6; j++) {
        float v = x0 * W1[0 * 6 + j] + x1 * W1[1 * 6 + j] + x2 * W1[2 * 6 + j] + b1[j];
        hbuf[j] = v / (1.0f + __expf(-v));   // SiLU
    }
    int j = sub & 3;
    float val;
    if (j == 0) {
        val = 1.0f;                           // degree increment
    } else {
        float v = b2[j - 1];
#pragma unroll
        for (int k = 0; k < 6; k++) v += hbuf[k] * W2[k * 3 + (j - 1)];
        val = v;
    }
    int side = sub >> 2;
    int node = side ? dst[e] : src[e];
    int slot = (side && j == 0) ? 4 : j;
    float old = atomicAdd(&nd[(size_t)node * 8 + slot], val);
    if (sub == 4) erank[e] = (int)old;        // rank among same-dst edges
}

// ---------------------------------------------------------------- scan phase 1: per-block excl scan + block sums
__global__ __launch_bounds__(1024) void scan1_kernel(const float* __restrict__ nd,
                                                     int* __restrict__ excl,
                                                     int* __restrict__ bsum, int N) {
    __shared__ int buf[1024];
    int t = threadIdx.x;
    int i = blockIdx.x * 1024 + t;
    int v = (i < N) ? (int)nd[(size_t)i * 8 + 4] : 0;
    buf[t] = v;
    __syncthreads();
    for (int d = 1; d < 1024; d <<= 1) {     // Hillis-Steele inclusive
        int x = (t >= d) ? buf[t - d] : 0;
        __syncthreads();
        buf[t] += x;
        __syncthreads();
    }
    if (i < N) excl[i] = buf[t] - v;
    if (t == 1023) bsum[blockIdx.x] = buf[1023];
}

// ---------------------------------------------------------------- scan phase 2+3 merged: add serial block-prefix
__global__ __launch_bounds__(1024) void scan3_kernel(const int* __restrict__ excl,
                                                     const int* __restrict__ bsum,
                                                     int* __restrict__ off, int N, int E) {
    __shared__ int base;
    if (threadIdx.x == 0) {
        int s = 0;
        for (int k = 0; k < (int)blockIdx.x; k++) s += bsum[k];   // nb <= 49, trivial
        base = s;
    }
    __syncthreads();
    int i = blockIdx.x * 1024 + threadIdx.x;
    if (i < N) off[i] = excl[i] + base;
    if (i == 0) off[N] = E;
}

// ---------------------------------------------------------------- finalize: bin ssrc + epilogue (h16, el, er)
// 256 threads = 2 nodes x 128 cols; bin slice is fire-and-forget plain stores.
__global__ __launch_bounds__(256) void finalize_kernel(
        const int* __restrict__ src, const int* __restrict__ dst,
        const int* __restrict__ eoff, const int* __restrict__ erank,
        int* __restrict__ ssrc, int E,
        const float* __restrict__ hbase, const float* __restrict__ nd,
        const float* __restrict__ W_fc,
        const float* __restrict__ attn_l, const float* __restrict__ attn_r,
        unsigned short* __restrict__ h16,
        float* __restrict__ el, float* __restrict__ er, int N) {
    int gtid = blockIdx.x * 256 + threadIdx.x;
    if (gtid < E) ssrc[eoff[dst[gtid]] + erank[gtid]] = src[gtid];

    int node = blockIdx.x * 2 + (threadIdx.x >> 7);
    if (node >= N) return;
    int o = threadIdx.x & 127;
    float hb = hbase[(size_t)node * 128 + o];
    float dg = nd[node * 8 + 0] + nd[node * 8 + 4];
    float hv = dg * hb
             + nd[node * 8 + 1] * W_fc[128 * 128 + o]
             + nd[node * 8 + 2] * W_fc[129 * 128 + o]
             + nd[node * 8 + 3] * W_fc[130 * 128 + o];
    h16[(size_t)node * 128 + o] = bf16rne(hv);
    float pl = hv * attn_l[o], pr = hv * attn_r[o];
#pragma unroll
    for (int mask = 1; mask <= 16; mask <<= 1) {   // reduce within 32-lane head group
        pl += __shfl_xor(pl, mask);
        pr += __shfl_xor(pr, mask);
    }
    if ((o & 31) == 0) {
        el[node * 4 + (o >> 5)] = pl;
        er[node * 4 + (o >> 5)] = pr;
    }
}

// ---------------------------------------------------------------- per-dst softmax + aggregate + LN + SiLU
// one wave = TWO nodes: 32 lanes each, 4 cols/lane (uint2 = 8B of bf16 h).
// Branchless exp-only softmax (shift-invariant; logits structurally small).
__global__ __launch_bounds__(256) void gather_kernel(
        const int* __restrict__ off, const int* __restrict__ sorted_src,
        const float* __restrict__ el, const float* __restrict__ er,
        const unsigned short* __restrict__ h16, const float* __restrict__ nf,
        const float* __restrict__ gat_bias, const float* __restrict__ gamma,
        const float* __restrict__ beta, float* __restrict__ out, int N) {
    int wid  = (blockIdx.x * blockDim.x + threadIdx.x) >> 6;
    int lane = threadIdx.x & 63;
    int half = lane >> 5;
    int li   = lane & 31;
    int n = wid * 2 + half;
    if (n >= N) return;                       // N even + exact grid: whole half-wave exits together
    int o0 = li * 4;                          // 4 cols per lane, same head
    int hd = li >> 3;
    float ern = er[(unsigned)(n * 4 + hd)];
    int beg = off[n], end = off[n + 1];
    float z = 0.f, a0 = 0.f, a1 = 0.f, a2 = 0.f, a3 = 0.f;
    if (beg < end) {
        int s = sorted_src[beg];
        float elv = el[(unsigned)(s * 4 + hd)];
        uint2 hb = *(const uint2*)&h16[(unsigned)(s * 128 + o0)];
        for (int j = beg; j < end; j++) {
            int s2 = (j + 1 < end) ? sorted_src[j + 1] : s;
            float elv2 = el[(unsigned)(s2 * 4 + hd)];
            uint2 hb2 = *(const uint2*)&h16[(unsigned)(s2 * 128 + o0)];
            float l = elv + ern;
            l = (l > 0.f) ? l : 0.2f * l;                   // leaky_relu(0.2)
            float p = __expf(l);
            z  += p;
            a0 += p * __uint_as_float(hb.x << 16);
            a1 += p * __uint_as_float(hb.x & 0xFFFF0000u);
            a2 += p * __uint_as_float(hb.y << 16);
            a3 += p * __uint_as_float(hb.y & 0xFFFF0000u);
            elv = elv2; hb = hb2; s = s2;
        }
    }
    float izv = (end > beg) ? 1.0f / z : 0.f;
    float4 nfv = *(const float4*)&nf[(size_t)n * 128 + o0];
    float v0 = a0 * izv + gat_bias[o0]     + nfv.x;
    float v1 = a1 * izv + gat_bias[o0 + 1] + nfv.y;
    float v2 = a2 * izv + gat_bias[o0 + 2] + nfv.z;
    float v3 = a3 * izv + gat_bias[o0 + 3] + nfv.w;
    float s  = v0 + v1 + v2 + v3;
    float s2 = v0 * v0 + v1 * v1 + v2 * v2 + v3 * v3;
#pragma unroll
    for (int mask = 1; mask <= 16; mask <<= 1) {   // reduce within the 32-lane half
        s  += __shfl_xor(s, mask);
        s2 += __shfl_xor(s2, mask);
    }
    float mu = s * (1.0f / 128.0f);
    float var = s2 * (1.0f / 128.0f) - mu * mu;
    float inv = rsqrtf(var + 1e-5f);
    float y0 = (v0 - mu) * inv * gamma[o0]     + beta[o0];
    float y1 = (v1 - mu) * inv * gamma[o0 + 1] + beta[o0 + 1];
    float y2 = (v2 - mu) * inv * gamma[o0 + 2] + beta[o0 + 2];
    float y3 = (v3 - mu) * inv * gamma[o0 + 3] + beta[o0 + 3];
    float4 ov;
    ov.x = y0 / (1.0f + __expf(-y0));
    ov.y = y1 / (1.0f + __expf(-y1));
    ov.z = y2 / (1.0f + __expf(-y2));
    ov.w = y3 / (1.0f + __expf(-y3));
    *(float4*)&out[(size_t)n * 128 + o0] = ov;
}

extern "C" void kernel_launch(void* const* d_in, const int* in_sizes, int n_in,
                              void* d_out, int out_size, void* d_ws, size_t ws_size,
                              hipStream_t stream) {
    const float* nf     = (const float*)d_in[0];
    const float* ef     = (const float*)d_in[1];
    const int*   src    = (const int*)d_in[2];
    const int*   dst    = (const int*)d_in[3];
    const float* W_em1  = (const float*)d_in[4];
    const float* b_em1  = (const float*)d_in[5];
    const float* W_em2  = (const float*)d_in[6];
    const float* b_em2  = (const float*)d_in[7];
    const float* W_np   = (const float*)d_in[8];
    const float* b_np   = (const float*)d_in[9];
    const float* W_fc   = (const float*)d_in[10];
    const float* attn_l = (const float*)d_in[11];
    const float* attn_r = (const float*)d_in[12];
    const float* g_bias = (const float*)d_in[13];
    const float* ln_g   = (const float*)d_in[14];
    const float* ln_b   = (const float*)d_in[15];

    const int N = in_sizes[0] / IN_FEAT;
    const int E = in_sizes[2];

    float* ws = (float*)d_ws;
    size_t off_w = 0;
    auto alloc = [&](size_t nelem) {
        float* p = ws + off_w;
        off_w += (nelem + 63) & ~(size_t)63;   // 256B-align
        return p;
    };
    float* nd    = alloc((size_t)N * 8);       // {outdeg, e0, e1, e2, indeg, pad, pad, pad}
    short* WBh   = (short*)alloc(128 * 128 / 2);   // fragment-ordered bf16 hi
    short* WBl   = (short*)alloc(128 * 128 / 2);   // lo
    float* bvec  = alloc(128);
    float* hbase = alloc((size_t)N * 128);     // nf@Wc + bvec (fp32, pre-epilogue)
    unsigned short* h16 = (unsigned short*)alloc((size_t)N * 64);   // N*128 bf16
    float* el    = alloc((size_t)N * 4);
    float* er    = alloc((size_t)N * 4);
    int*   erank  = (int*)alloc(E);
    int*   eoff   = (int*)alloc(N + 1);
    int*   ssrc   = (int*)alloc(E);
    int*   excl   = (int*)alloc(N);
    int*   bsum   = (int*)alloc(1024);

    const int nb = (N + 1023) / 1024;
    const int gemmBlocks = (N + 63) / 64;
    const int scatBlocks = (int)(((size_t)E * 8 + 255) / 256);
    const int totBlocks  = gemmBlocks + scatBlocks;
    int S = totBlocks / gemmBlocks;            // interleave stride (>=1)
    if (S < 1) S = 1;
    // coverage: (gemmBlocks-1)*S must be < totBlocks  (holds since S = floor(tot/gemm))

    wcomb_kernel<<<128, 128, 0, stream>>>(W_np, W_fc, b_np, WBh, WBl, bvec,
                                          (float4*)nd, N * 2);
    fused_kernel<<<totBlocks, 256, 0, stream>>>(
        ef, src, dst, W_em1, b_em1, W_em2, b_em2, nd, erank, E,
        nf, WBh, WBl, bvec, hbase, N, gemmBlocks, S);
    scan1_kernel<<<nb, 1024, 0, stream>>>(nd, excl, bsum, N);
    scan3_kernel<<<nb, 1024, 0, stream>>>(excl, bsum, eoff, N, E);
    finalize_kernel<<<(N + 1) / 2, 256, 0, stream>>>(src, dst, eoff, erank, ssrc, E,
                                                     hbase, nd, W_fc, attn_l, attn_r,
                                                     h16, el, er, N);
    gather_kernel<<<((size_t)N * 32 + 255) / 256, 256, 0, stream>>>(eoff, ssrc, el, er, h16, nf,
                                                                    g_bias, ln_g, ln_b,
                                                                    (float*)d_out, N);
}

// Round 13
// 151.448 us; speedup vs baseline: 1.2429x; 1.2429x over previous
//
#include <hip/hip_runtime.h>
#include <hip/hip_bf16.h>

#define IN_FEAT 128
#define N_HEADS 4
#define OUT_FEAT 32

typedef __attribute__((ext_vector_type(8))) short short8;
typedef __attribute__((ext_vector_type(4))) float floatx4;

// RNE float -> bf16 (hi) + bf16 residual (lo)
__device__ __forceinline__ void bf16split(float x, short& hi, short& lo) {
    unsigned u = __float_as_uint(x);
    unsigned r = (u + 0x7FFFu + ((u >> 16) & 1u)) & 0xFFFF0000u;
    hi = (short)(r >> 16);
    float res = x - __uint_as_float(r);
    unsigned u2 = __float_as_uint(res);
    unsigned r2 = u2 + 0x7FFFu + ((u2 >> 16) & 1u);
    lo = (short)(r2 >> 16);
}

__device__ __forceinline__ unsigned short bf16rne(float x) {
    unsigned u = __float_as_uint(x);
    return (unsigned short)((u + 0x7FFFu + ((u >> 16) & 1u)) >> 16);
}

// ---------------------------------------------------------------- fused edge MLP + 2-sector scatter
// nd[n*8 + {0..4}] = {outdeg, e0, e1, e2, indeg};  8 lanes/edge (R8 form, measured 62us)
__global__ void edge_scatter_kernel(const float* __restrict__ ef,
                                    const int* __restrict__ src, const int* __restrict__ dst,
                                    const float* __restrict__ W1, const float* __restrict__ b1,
                                    const float* __restrict__ W2, const float* __restrict__ b2,
                                    float* __restrict__ nd, int* __restrict__ erank, int E) {
    int t = blockIdx.x * blockDim.x + threadIdx.x;
    int e = t >> 3;
    int sub = t & 7;
    if (e >= E) return;
    float x0 = ef[e * 3 + 0], x1 = ef[e * 3 + 1], x2 = ef[e * 3 + 2];
    float hbuf[6];
#pragma unroll
    for (int j = 0; j < 6; j++) {
        float v = x0 * W1[0 * 6 + j] + x1 * W1[1 * 6 + j] + x2 * W1[2 * 6 + j] + b1[j];
        hbuf[j] = v / (1.0f + __expf(-v));   // SiLU
    }
    int j = sub & 3;
    float val;
    if (j == 0) {
        val = 1.0f;                           // degree increment
    } else {
        float v = b2[j - 1];
#pragma unroll
        for (int k = 0; k < 6; k++) v += hbuf[k] * W2[k * 3 + (j - 1)];
        val = v;
    }
    int side = sub >> 2;
    int node = side ? dst[e] : src[e];
    int slot = (side && j == 0) ? 4 : j;
    float old = atomicAdd(&nd[(size_t)node * 8 + slot], val);
    if (sub == 4) erank[e] = (int)old;        // rank among same-dst edges
}

// ---------------------------------------------------------------- scan phase 1: per-block excl scan + block sums
__global__ __launch_bounds__(1024) void scan1_kernel(const float* __restrict__ nd,
                                                     int* __restrict__ excl,
                                                     int* __restrict__ bsum, int N) {
    __shared__ int buf[1024];
    int t = threadIdx.x;
    int i = blockIdx.x * 1024 + t;
    int v = (i < N) ? (int)nd[(size_t)i * 8 + 4] : 0;
    buf[t] = v;
    __syncthreads();
    for (int d = 1; d < 1024; d <<= 1) {     // Hillis-Steele inclusive
        int x = (t >= d) ? buf[t - d] : 0;
        __syncthreads();
        buf[t] += x;
        __syncthreads();
    }
    if (i < N) excl[i] = buf[t] - v;
    if (t == 1023) bsum[blockIdx.x] = buf[1023];
}

// ---------------------------------------------------------------- scan phase 2+3 merged: add serial block-prefix
__global__ __launch_bounds__(1024) void scan3_kernel(const int* __restrict__ excl,
                                                     const int* __restrict__ bsum,
                                                     int* __restrict__ off, int N, int E) {
    __shared__ int base;
    if (threadIdx.x == 0) {
        int s = 0;
        for (int k = 0; k < (int)blockIdx.x; k++) s += bsum[k];   // nb <= 49, trivial
        base = s;
    }
    __syncthreads();
    int i = blockIdx.x * 1024 + threadIdx.x;
    if (i < N) off[i] = excl[i] + base;
    if (i == 0) off[N] = E;
}

// ---------------------------------------------------------------- wcomb (fragment-ordered bf16 hi/lo) + zero nd
// frag layout for mfma_f32_16x16x32_bf16 B-operand: lane l holds B[k][o] with
// o = t*16 + (l&15), k = kk*32 + (l>>4)*8 + j  ->  flat idx ((t*4+kk)*64 + l)*8 + j
__global__ void wcomb_kernel(const float* __restrict__ W_np, const float* __restrict__ W_fc,
                             const float* __restrict__ b_np,
                             short* __restrict__ WBh, short* __restrict__ WBl,
                             float* __restrict__ bvec,
                             float4* __restrict__ ndz, int zcnt) {
    for (int i = blockIdx.x * blockDim.x + threadIdx.x; i < zcnt; i += gridDim.x * blockDim.x)
        ndz[i] = (float4){0.f, 0.f, 0.f, 0.f};

    int i = blockIdx.x;      // 0..127 (k row of Wc)
    int o = threadIdx.x;     // 0..127 (output col)
    float acc = 0.0f;
    for (int j = 0; j < 128; j++) acc += W_np[i * 128 + j] * W_fc[j * 128 + o];
    short hi, lo;
    bf16split(acc, hi, lo);
    int t    = o >> 4;
    int kk   = i >> 5;
    int lane = ((i >> 3) & 3) * 16 + (o & 15);
    int jj   = i & 7;
    int fi = ((t * 4 + kk) * 64 + lane) * 8 + jj;
    WBh[fi] = hi;
    WBl[fi] = lo;
    if (i == 0) {
        float bb = 0.0f;
        for (int j = 0; j < 128; j++) bb += b_np[j] * W_fc[j * 128 + o];
        bvec[o] = bb;
    }
}

// ---------------------------------------------------------------- fused: bin (scatter ssrc) + node GEMM + epilogue
// Runs AFTER scans: no atomic storm -> WB global reads are L2-warm.
// bin stores are fire-and-forget; they drain under the MFMA/epilogue work.
// GEMM: A plain bf16 (RNE), B split hi/lo -> 2 MFMAs per (t,kk).
__global__ __launch_bounds__(256) void binh_kernel(
        const int* __restrict__ src, const int* __restrict__ dst,
        const int* __restrict__ eoff, const int* __restrict__ erank,
        int* __restrict__ ssrc, int E,
        const float* __restrict__ nf,
        const short* __restrict__ WBh, const short* __restrict__ WBl,
        const float* __restrict__ bvec, const float* __restrict__ W_fc,
        const float* __restrict__ nd,
        const float* __restrict__ attn_l, const float* __restrict__ attn_r,
        unsigned short* __restrict__ h16,
        float* __restrict__ el, float* __restrict__ er, int N) {
    // ---- bin slice: fire-and-forget scattered stores
    {
        int stride = gridDim.x * 256;
        for (int e = blockIdx.x * 256 + threadIdx.x; e < E; e += stride) {
            ssrc[eoff[dst[e]] + erank[e]] = src[e];
        }
    }

    // ---- GEMM: 64 nodes/block (16/wave), full 128 cols
    const int w = threadIdx.x >> 6, l = threadIdx.x & 63;
    const int lrow = l & 15, lhalf = l >> 4;
    const int n0 = blockIdx.x * 64 + w * 16;
    const int arow = n0 + lrow;

    short8 ah[4];
#pragma unroll
    for (int kk = 0; kk < 4; kk++) {
        float v[8];
        if (arow < N) {
            const float* p = &nf[(size_t)arow * 128 + kk * 32 + lhalf * 8];
            float4 f0 = *(const float4*)p;
            float4 f1 = *(const float4*)(p + 4);
            v[0] = f0.x; v[1] = f0.y; v[2] = f0.z; v[3] = f0.w;
            v[4] = f1.x; v[5] = f1.y; v[6] = f1.z; v[7] = f1.w;
        } else {
#pragma unroll
            for (int j = 0; j < 8; j++) v[j] = 0.0f;
        }
#pragma unroll
        for (int j = 0; j < 8; j++) ah[kk][j] = (short)bf16rne(v[j]);
    }

    const short8* gbh = (const short8*)WBh;
    const short8* gbl = (const short8*)WBl;
    floatx4 acc[8];
#pragma unroll
    for (int t = 0; t < 8; t++) acc[t] = (floatx4){0.f, 0.f, 0.f, 0.f};
#pragma unroll
    for (int t = 0; t < 8; t++) {
#pragma unroll
        for (int kk = 0; kk < 4; kk++) {
            short8 bh = gbh[(t * 4 + kk) * 64 + l];
            short8 bl = gbl[(t * 4 + kk) * 64 + l];
            acc[t] = __builtin_amdgcn_mfma_f32_16x16x32_bf16(ah[kk], bh, acc[t], 0, 0, 0);
            acc[t] = __builtin_amdgcn_mfma_f32_16x16x32_bf16(ah[kk], bl, acc[t], 0, 0, 0);
        }
    }

    // ---- epilogue: h = deg*(acc+bvec) + esum@W_fc[128:131]; h16/el/er (verified R6-R10 form)
    float bv[8], w0[8], w1[8], w2[8], alb[8], arb[8];
#pragma unroll
    for (int t = 0; t < 8; t++) {
        int o = t * 16 + lrow;
        bv[t] = bvec[o];
        w0[t] = W_fc[128 * 128 + o];
        w1[t] = W_fc[129 * 128 + o];
        w2[t] = W_fc[130 * 128 + o];
        alb[t] = attn_l[o];
        arb[t] = attn_r[o];
    }
#pragma unroll
    for (int r = 0; r < 4; r++) {
        int node = n0 + lhalf * 4 + r;
        bool valid = node < N;
        float dg = 0.f, e0 = 0.f, e1 = 0.f, e2 = 0.f;
        if (valid) {
            dg = nd[(size_t)node * 8 + 0] + nd[(size_t)node * 8 + 4];
            e0 = nd[(size_t)node * 8 + 1];
            e1 = nd[(size_t)node * 8 + 2];
            e2 = nd[(size_t)node * 8 + 3];
        }
        float pl[4] = {0.f, 0.f, 0.f, 0.f}, pr[4] = {0.f, 0.f, 0.f, 0.f};
#pragma unroll
        for (int t = 0; t < 8; t++) {
            float hv = dg * (acc[t][r] + bv[t]) + e0 * w0[t] + e1 * w1[t] + e2 * w2[t];
            if (valid) h16[(size_t)node * 128 + t * 16 + lrow] = bf16rne(hv);
            pl[t >> 1] += hv * alb[t];
            pr[t >> 1] += hv * arb[t];
        }
#pragma unroll
        for (int hd = 0; hd < 4; hd++) {
#pragma unroll
            for (int mask = 1; mask <= 8; mask <<= 1) {
                pl[hd] += __shfl_xor(pl[hd], mask);
                pr[hd] += __shfl_xor(pr[hd], mask);
            }
        }
        if (valid) {
            if (lrow < 4)      el[node * 4 + lrow]       = pl[lrow];
            else if (lrow < 8) er[node * 4 + (lrow - 4)] = pr[lrow - 4];
        }
    }
}

// ---------------------------------------------------------------- per-dst softmax + aggregate + LN + SiLU
// one wave = TWO nodes: 32 lanes each, 4 cols/lane (uint2 = 8B of bf16 h).
// Branchless exp-only softmax (shift-invariant; logits structurally small).
__global__ __launch_bounds__(256) void gather_kernel(
        const int* __restrict__ off, const int* __restrict__ sorted_src,
        const float* __restrict__ el, const float* __restrict__ er,
        const unsigned short* __restrict__ h16, const float* __restrict__ nf,
        const float* __restrict__ gat_bias, const float* __restrict__ gamma,
        const float* __restrict__ beta, float* __restrict__ out, int N) {
    int wid  = (blockIdx.x * blockDim.x + threadIdx.x) >> 6;
    int lane = threadIdx.x & 63;
    int half = lane >> 5;
    int li   = lane & 31;
    int n = wid * 2 + half;
    if (n >= N) return;                       // N even + exact grid: whole half-wave exits together
    int o0 = li * 4;                          // 4 cols per lane, same head
    int hd = li >> 3;
    float ern = er[(unsigned)(n * 4 + hd)];
    int beg = off[n], end = off[n + 1];
    float z = 0.f, a0 = 0.f, a1 = 0.f, a2 = 0.f, a3 = 0.f;
    if (beg < end) {
        int s = sorted_src[beg];
        float elv = el[(unsigned)(s * 4 + hd)];
        uint2 hb = *(const uint2*)&h16[(unsigned)(s * 128 + o0)];
        for (int j = beg; j < end; j++) {
            int s2 = (j + 1 < end) ? sorted_src[j + 1] : s;
            float elv2 = el[(unsigned)(s2 * 4 + hd)];
            uint2 hb2 = *(const uint2*)&h16[(unsigned)(s2 * 128 + o0)];
            float l = elv + ern;
            l = (l > 0.f) ? l : 0.2f * l;                   // leaky_relu(0.2)
            float p = __expf(l);
            z  += p;
            a0 += p * __uint_as_float(hb.x << 16);
            a1 += p * __uint_as_float(hb.x & 0xFFFF0000u);
            a2 += p * __uint_as_float(hb.y << 16);
            a3 += p * __uint_as_float(hb.y & 0xFFFF0000u);
            elv = elv2; hb = hb2; s = s2;
        }
    }
    float izv = (end > beg) ? 1.0f / z : 0.f;
    float4 nfv = *(const float4*)&nf[(size_t)n * 128 + o0];
    float v0 = a0 * izv + gat_bias[o0]     + nfv.x;
    float v1 = a1 * izv + gat_bias[o0 + 1] + nfv.y;
    float v2 = a2 * izv + gat_bias[o0 + 2] + nfv.z;
    float v3 = a3 * izv + gat_bias[o0 + 3] + nfv.w;
    float s  = v0 + v1 + v2 + v3;
    float s2 = v0 * v0 + v1 * v1 + v2 * v2 + v3 * v3;
#pragma unroll
    for (int mask = 1; mask <= 16; mask <<= 1) {   // reduce within the 32-lane half
        s  += __shfl_xor(s, mask);
        s2 += __shfl_xor(s2, mask);
    }
    float mu = s * (1.0f / 128.0f);
    float var = s2 * (1.0f / 128.0f) - mu * mu;
    float inv = rsqrtf(var + 1e-5f);
    float y0 = (v0 - mu) * inv * gamma[o0]     + beta[o0];
    float y1 = (v1 - mu) * inv * gamma[o0 + 1] + beta[o0 + 1];
    float y2 = (v2 - mu) * inv * gamma[o0 + 2] + beta[o0 + 2];
    float y3 = (v3 - mu) * inv * gamma[o0 + 3] + beta[o0 + 3];
    float4 ov;
    ov.x = y0 / (1.0f + __expf(-y0));
    ov.y = y1 / (1.0f + __expf(-y1));
    ov.z = y2 / (1.0f + __expf(-y2));
    ov.w = y3 / (1.0f + __expf(-y3));
    *(float4*)&out[(size_t)n * 128 + o0] = ov;
}

extern "C" void kernel_launch(void* const* d_in, const int* in_sizes, int n_in,
                              void* d_out, int out_size, void* d_ws, size_t ws_size,
                              hipStream_t stream) {
    const float* nf     = (const float*)d_in[0];
    const float* ef     = (const float*)d_in[1];
    const int*   src    = (const int*)d_in[2];
    const int*   dst    = (const int*)d_in[3];
    const float* W_em1  = (const float*)d_in[4];
    const float* b_em1  = (const float*)d_in[5];
    const float* W_em2  = (const float*)d_in[6];
    const float* b_em2  = (const float*)d_in[7];
    const float* W_np   = (const float*)d_in[8];
    const float* b_np   = (const float*)d_in[9];
    const float* W_fc   = (const float*)d_in[10];
    const float* attn_l = (const float*)d_in[11];
    const float* attn_r = (const float*)d_in[12];
    const float* g_bias = (const float*)d_in[13];
    const float* ln_g   = (const float*)d_in[14];
    const float* ln_b   = (const float*)d_in[15];

    const int N = in_sizes[0] / IN_FEAT;
    const int E = in_sizes[2];

    float* ws = (float*)d_ws;
    size_t off_w = 0;
    auto alloc = [&](size_t nelem) {
        float* p = ws + off_w;
        off_w += (nelem + 63) & ~(size_t)63;   // 256B-align
        return p;
    };
    float* nd    = alloc((size_t)N * 8);       // {outdeg, e0, e1, e2, indeg, pad, pad, pad}
    short* WBh   = (short*)alloc(128 * 128 / 2);   // fragment-ordered bf16 hi
    short* WBl   = (short*)alloc(128 * 128 / 2);   // lo
    float* bvec  = alloc(128);
    unsigned short* h16 = (unsigned short*)alloc((size_t)N * 64);   // N*128 bf16
    float* el    = alloc((size_t)N * 4);
    float* er    = alloc((size_t)N * 4);
    int*   erank  = (int*)alloc(E);
    int*   eoff   = (int*)alloc(N + 1);
    int*   ssrc   = (int*)alloc(E);
    int*   excl   = (int*)alloc(N);
    int*   bsum   = (int*)alloc(1024);

    const int nb = (N + 1023) / 1024;

    wcomb_kernel<<<128, 128, 0, stream>>>(W_np, W_fc, b_np, WBh, WBl, bvec,
                                          (float4*)nd, N * 2);
    edge_scatter_kernel<<<((size_t)E * 8 + 255) / 256, 256, 0, stream>>>(
        ef, src, dst, W_em1, b_em1, W_em2, b_em2, nd, erank, E);
    scan1_kernel<<<nb, 1024, 0, stream>>>(nd, excl, bsum, N);
    scan3_kernel<<<nb, 1024, 0, stream>>>(excl, bsum, eoff, N, E);
    binh_kernel<<<(N + 63) / 64, 256, 0, stream>>>(src, dst, eoff, erank, ssrc, E,
                                                   nf, WBh, WBl, bvec, W_fc, nd,
                                                   attn_l, attn_r, h16, el, er, N);
    gather_kernel<<<((size_t)N * 32 + 255) / 256, 256, 0, stream>>>(eoff, ssrc, el, er, h16, nf,
                                                                    g_bias, ln_g, ln_b,
                                                                    (float*)d_out, N);
}

// Round 14
// 148.130 us; speedup vs baseline: 1.2708x; 1.0224x over previous
//
#include <hip/hip_runtime.h>
#include <hip/hip_bf16.h>

#define IN_FEAT 128
#define N_HEADS 4
#define OUT_FEAT 32

typedef __attribute__((ext_vector_type(8))) short short8;
typedef __attribute__((ext_vector_type(4))) float floatx4;

// RNE float -> bf16 (hi) + bf16 residual (lo)
__device__ __forceinline__ void bf16split(float x, short& hi, short& lo) {
    unsigned u = __float_as_uint(x);
    unsigned r = (u + 0x7FFFu + ((u >> 16) & 1u)) & 0xFFFF0000u;
    hi = (short)(r >> 16);
    float res = x - __uint_as_float(r);
    unsigned u2 = __float_as_uint(res);
    unsigned r2 = u2 + 0x7FFFu + ((u2 >> 16) & 1u);
    lo = (short)(r2 >> 16);
}

__device__ __forceinline__ unsigned short bf16rne(float x) {
    unsigned u = __float_as_uint(x);
    return (unsigned short)((u + 0x7FFFu + ((u >> 16) & 1u)) >> 16);
}

// ---------------------------------------------------------------- fused edge MLP + 2-sector scatter
// nd[n*8 + {0..4}] = {outdeg, e0, e1, e2, indeg};  8 lanes/edge (measured 62us, atomic-sector wall)
__global__ void edge_scatter_kernel(const float* __restrict__ ef,
                                    const int* __restrict__ src, const int* __restrict__ dst,
                                    const float* __restrict__ W1, const float* __restrict__ b1,
                                    const float* __restrict__ W2, const float* __restrict__ b2,
                                    float* __restrict__ nd, int* __restrict__ erank, int E) {
    int t = blockIdx.x * blockDim.x + threadIdx.x;
    int e = t >> 3;
    int sub = t & 7;
    if (e >= E) return;
    float x0 = ef[e * 3 + 0], x1 = ef[e * 3 + 1], x2 = ef[e * 3 + 2];
    float hbuf[6];
#pragma unroll
    for (int j = 0; j < 6; j++) {
        float v = x0 * W1[0 * 6 + j] + x1 * W1[1 * 6 + j] + x2 * W1[2 * 6 + j] + b1[j];
        hbuf[j] = v / (1.0f + __expf(-v));   // SiLU
    }
    int j = sub & 3;
    float val;
    if (j == 0) {
        val = 1.0f;                           // degree increment
    } else {
        float v = b2[j - 1];
#pragma unroll
        for (int k = 0; k < 6; k++) v += hbuf[k] * W2[k * 3 + (j - 1)];
        val = v;
    }
    int side = sub >> 2;
    int node = side ? dst[e] : src[e];
    int slot = (side && j == 0) ? 4 : j;
    float old = atomicAdd(&nd[(size_t)node * 8 + slot], val);
    if (sub == 4) erank[e] = (int)old;        // rank among same-dst edges
}

// ---------------------------------------------------------------- scan phase 1: per-block excl scan + block sums
__global__ __launch_bounds__(1024) void scan1_kernel(const float* __restrict__ nd,
                                                     int* __restrict__ excl,
                                                     int* __restrict__ bsum, int N) {
    __shared__ int buf[1024];
    int t = threadIdx.x;
    int i = blockIdx.x * 1024 + t;
    int v = (i < N) ? (int)nd[(size_t)i * 8 + 4] : 0;
    buf[t] = v;
    __syncthreads();
    for (int d = 1; d < 1024; d <<= 1) {     // Hillis-Steele inclusive
        int x = (t >= d) ? buf[t - d] : 0;
        __syncthreads();
        buf[t] += x;
        __syncthreads();
    }
    if (i < N) excl[i] = buf[t] - v;
    if (t == 1023) bsum[blockIdx.x] = buf[1023];
}

// ---------------------------------------------------------------- scan phase 2+3 merged: add serial block-prefix
__global__ __launch_bounds__(1024) void scan3_kernel(const int* __restrict__ excl,
                                                     const int* __restrict__ bsum,
                                                     int* __restrict__ off, int N, int E) {
    __shared__ int base;
    if (threadIdx.x == 0) {
        int s = 0;
        for (int k = 0; k < (int)blockIdx.x; k++) s += bsum[k];   // nb <= 49, trivial
        base = s;
    }
    __syncthreads();
    int i = blockIdx.x * 1024 + threadIdx.x;
    if (i < N) off[i] = excl[i] + base;
    if (i == 0) off[N] = E;
}

// ---------------------------------------------------------------- wcomb (fragment-ordered bf16 hi/lo) + zero nd
// frag layout for mfma_f32_16x16x32_bf16 B-operand: lane l holds B[k][o] with
// o = t*16 + (l&15), k = kk*32 + (l>>4)*8 + j  ->  flat idx ((t*4+kk)*64 + l)*8 + j
__global__ void wcomb_kernel(const float* __restrict__ W_np, const float* __restrict__ W_fc,
                             const float* __restrict__ b_np,
                             short* __restrict__ WBh, short* __restrict__ WBl,
                             float* __restrict__ bvec,
                             float4* __restrict__ ndz, int zcnt) {
    for (int i = blockIdx.x * blockDim.x + threadIdx.x; i < zcnt; i += gridDim.x * blockDim.x)
        ndz[i] = (float4){0.f, 0.f, 0.f, 0.f};

    int i = blockIdx.x;      // 0..127 (k row of Wc)
    int o = threadIdx.x;     // 0..127 (output col)
    float acc = 0.0f;
    for (int j = 0; j < 128; j++) acc += W_np[i * 128 + j] * W_fc[j * 128 + o];
    short hi, lo;
    bf16split(acc, hi, lo);
    int t    = o >> 4;
    int kk   = i >> 5;
    int lane = ((i >> 3) & 3) * 16 + (o & 15);
    int jj   = i & 7;
    int fi = ((t * 4 + kk) * 64 + lane) * 8 + jj;
    WBh[fi] = hi;
    WBl[fi] = lo;
    if (i == 0) {
        float bb = 0.0f;
        for (int j = 0; j < 128; j++) bb += b_np[j] * W_fc[j * 128 + o];
        bvec[o] = bb;
    }
}

// ---------------------------------------------------------------- fused: bin (scatter ssrc) + node GEMM + epilogue
// LDS-staged WB (R6-proven: amortizes L2 latency into one coalesced block copy).
// bin loop AFTER __syncthreads so its scattered stores drain under the MFMA work
// (no later barrier). GEMM: A plain bf16 (RNE), B split hi/lo -> 2 MFMAs.
__global__ __launch_bounds__(256) void binh_kernel(
        const int* __restrict__ src, const int* __restrict__ dst,
        const int* __restrict__ eoff, const int* __restrict__ erank,
        int* __restrict__ ssrc, int E,
        const float* __restrict__ nf,
        const short* __restrict__ WBh, const short* __restrict__ WBl,
        const float* __restrict__ bvec, const float* __restrict__ W_fc,
        const float* __restrict__ nd,
        const float* __restrict__ attn_l, const float* __restrict__ attn_r,
        unsigned short* __restrict__ h16,
        float* __restrict__ el, float* __restrict__ er, int N) {
    __shared__ short lWh[16384];   // 32 KB fragment-ordered Wc hi
    __shared__ short lWl[16384];   // 32 KB fragment-ordered Wc lo
    {
        const int4* s1 = (const int4*)WBh;
        const int4* s2 = (const int4*)WBl;
        int4* d1 = (int4*)lWh;
        int4* d2 = (int4*)lWl;
        for (int i = threadIdx.x; i < 2048; i += 256) { d1[i] = s1[i]; d2[i] = s2[i]; }
    }
    __syncthreads();

    // ---- bin slice: fire-and-forget scattered stores (drain under MFMA below)
    {
        int stride = gridDim.x * 256;
        for (int e = blockIdx.x * 256 + threadIdx.x; e < E; e += stride) {
            ssrc[eoff[dst[e]] + erank[e]] = src[e];
        }
    }

    // ---- GEMM: 64 nodes/block (16/wave), full 128 cols
    const int w = threadIdx.x >> 6, l = threadIdx.x & 63;
    const int lrow = l & 15, lhalf = l >> 4;
    const int n0 = blockIdx.x * 64 + w * 16;
    const int arow = n0 + lrow;

    short8 ah[4];
#pragma unroll
    for (int kk = 0; kk < 4; kk++) {
        float v[8];
        if (arow < N) {
            const float* p = &nf[(size_t)arow * 128 + kk * 32 + lhalf * 8];
            float4 f0 = *(const float4*)p;
            float4 f1 = *(const float4*)(p + 4);
            v[0] = f0.x; v[1] = f0.y; v[2] = f0.z; v[3] = f0.w;
            v[4] = f1.x; v[5] = f1.y; v[6] = f1.z; v[7] = f1.w;
        } else {
#pragma unroll
            for (int j = 0; j < 8; j++) v[j] = 0.0f;
        }
#pragma unroll
        for (int j = 0; j < 8; j++) ah[kk][j] = (short)bf16rne(v[j]);
    }

    floatx4 acc[8];
#pragma unroll
    for (int t = 0; t < 8; t++) acc[t] = (floatx4){0.f, 0.f, 0.f, 0.f};
#pragma unroll
    for (int t = 0; t < 8; t++) {
#pragma unroll
        for (int kk = 0; kk < 4; kk++) {
            int fi = ((t * 4 + kk) * 64 + l) * 8;
            short8 bh = *(const short8*)&lWh[fi];
            short8 bl = *(const short8*)&lWl[fi];
            acc[t] = __builtin_amdgcn_mfma_f32_16x16x32_bf16(ah[kk], bh, acc[t], 0, 0, 0);
            acc[t] = __builtin_amdgcn_mfma_f32_16x16x32_bf16(ah[kk], bl, acc[t], 0, 0, 0);
        }
    }

    // ---- epilogue: h = deg*(acc+bvec) + esum@W_fc[128:131]; h16/el/er
    float bv[8], w0[8], w1[8], w2[8], alb[8], arb[8];
#pragma unroll
    for (int t = 0; t < 8; t++) {
        int o = t * 16 + lrow;
        bv[t] = bvec[o];
        w0[t] = W_fc[128 * 128 + o];
        w1[t] = W_fc[129 * 128 + o];
        w2[t] = W_fc[130 * 128 + o];
        alb[t] = attn_l[o];
        arb[t] = attn_r[o];
    }
#pragma unroll
    for (int r = 0; r < 4; r++) {
        int node = n0 + lhalf * 4 + r;
        bool valid = node < N;
        float dg = 0.f, e0 = 0.f, e1 = 0.f, e2 = 0.f;
        if (valid) {
            dg = nd[(size_t)node * 8 + 0] + nd[(size_t)node * 8 + 4];
            e0 = nd[(size_t)node * 8 + 1];
            e1 = nd[(size_t)node * 8 + 2];
            e2 = nd[(size_t)node * 8 + 3];
        }
        float pl[4] = {0.f, 0.f, 0.f, 0.f}, pr[4] = {0.f, 0.f, 0.f, 0.f};
#pragma unroll
        for (int t = 0; t < 8; t++) {
            float hv = dg * (acc[t][r] + bv[t]) + e0 * w0[t] + e1 * w1[t] + e2 * w2[t];
            if (valid) h16[(size_t)node * 128 + t * 16 + lrow] = bf16rne(hv);
            pl[t >> 1] += hv * alb[t];
            pr[t >> 1] += hv * arb[t];
        }
#pragma unroll
        for (int hd = 0; hd < 4; hd++) {
#pragma unroll
            for (int mask = 1; mask <= 8; mask <<= 1) {
                pl[hd] += __shfl_xor(pl[hd], mask);
                pr[hd] += __shfl_xor(pr[hd], mask);
            }
        }
        if (valid) {
            if (lrow < 4)      el[node * 4 + lrow]       = pl[lrow];
            else if (lrow < 8) er[node * 4 + (lrow - 4)] = pr[lrow - 4];
        }
    }
}

// ---------------------------------------------------------------- per-dst softmax + aggregate + LN + SiLU
// one wave = TWO nodes: 32 lanes each, 4 cols/lane.  2 edges per iteration:
// independent exp/FMA chains double ILP, loads batch at iteration top.
__global__ __launch_bounds__(256) void gather_kernel(
        const int* __restrict__ off, const int* __restrict__ sorted_src,
        const float* __restrict__ el, const float* __restrict__ er,
        const unsigned short* __restrict__ h16, const float* __restrict__ nf,
        const float* __restrict__ gat_bias, const float* __restrict__ gamma,
        const float* __restrict__ beta, float* __restrict__ out, int N) {
    int wid  = (blockIdx.x * blockDim.x + threadIdx.x) >> 6;
    int lane = threadIdx.x & 63;
    int half = lane >> 5;
    int li   = lane & 31;
    int n = wid * 2 + half;
    if (n >= N) return;                       // N even + exact grid: whole half-wave exits together
    int o0 = li * 4;                          // 4 cols per lane, same head
    int hd = li >> 3;
    float ern = er[(unsigned)(n * 4 + hd)];
    int beg = off[n], end = off[n + 1];
    float z = 0.f, a0 = 0.f, a1 = 0.f, a2 = 0.f, a3 = 0.f;
    int j = beg;
    if ((end - beg) & 1) {                    // peel odd edge
        int s = sorted_src[j++];
        float l = el[(unsigned)(s * 4 + hd)] + ern;
        l = (l > 0.f) ? l : 0.2f * l;
        float p = __expf(l);
        uint2 hb = *(const uint2*)&h16[(unsigned)(s * 128 + o0)];
        z  = p;
        a0 = p * __uint_as_float(hb.x << 16);
        a1 = p * __uint_as_float(hb.x & 0xFFFF0000u);
        a2 = p * __uint_as_float(hb.y << 16);
        a3 = p * __uint_as_float(hb.y & 0xFFFF0000u);
    }
    for (; j < end; j += 2) {
        int sA = sorted_src[j];
        int sB = sorted_src[j + 1];
        float elA = el[(unsigned)(sA * 4 + hd)];
        float elB = el[(unsigned)(sB * 4 + hd)];
        uint2 hA = *(const uint2*)&h16[(unsigned)(sA * 128 + o0)];
        uint2 hB = *(const uint2*)&h16[(unsigned)(sB * 128 + o0)];
        float lA = elA + ern; lA = (lA > 0.f) ? lA : 0.2f * lA;
        float lB = elB + ern; lB = (lB > 0.f) ? lB : 0.2f * lB;
        float pA = __expf(lA);
        float pB = __expf(lB);
        z  += pA + pB;
        a0 += pA * __uint_as_float(hA.x << 16)         + pB * __uint_as_float(hB.x << 16);
        a1 += pA * __uint_as_float(hA.x & 0xFFFF0000u) + pB * __uint_as_float(hB.x & 0xFFFF0000u);
        a2 += pA * __uint_as_float(hA.y << 16)         + pB * __uint_as_float(hB.y << 16);
        a3 += pA * __uint_as_float(hA.y & 0xFFFF0000u) + pB * __uint_as_float(hB.y & 0xFFFF0000u);
    }
    float izv = (end > beg) ? 1.0f / z : 0.f;
    float4 nfv = *(const float4*)&nf[(size_t)n * 128 + o0];
    float v0 = a0 * izv + gat_bias[o0]     + nfv.x;
    float v1 = a1 * izv + gat_bias[o0 + 1] + nfv.y;
    float v2 = a2 * izv + gat_bias[o0 + 2] + nfv.z;
    float v3 = a3 * izv + gat_bias[o0 + 3] + nfv.w;
    float s  = v0 + v1 + v2 + v3;
    float s2 = v0 * v0 + v1 * v1 + v2 * v2 + v3 * v3;
#pragma unroll
    for (int mask = 1; mask <= 16; mask <<= 1) {   // reduce within the 32-lane half
        s  += __shfl_xor(s, mask);
        s2 += __shfl_xor(s2, mask);
    }
    float mu = s * (1.0f / 128.0f);
    float var = s2 * (1.0f / 128.0f) - mu * mu;
    float inv = rsqrtf(var + 1e-5f);
    float y0 = (v0 - mu) * inv * gamma[o0]     + beta[o0];
    float y1 = (v1 - mu) * inv * gamma[o0 + 1] + beta[o0 + 1];
    float y2 = (v2 - mu) * inv * gamma[o0 + 2] + beta[o0 + 2];
    float y3 = (v3 - mu) * inv * gamma[o0 + 3] + beta[o0 + 3];
    float4 ov;
    ov.x = y0 / (1.0f + __expf(-y0));
    ov.y = y1 / (1.0f + __expf(-y1));
    ov.z = y2 / (1.0f + __expf(-y2));
    ov.w = y3 / (1.0f + __expf(-y3));
    *(float4*)&out[(size_t)n * 128 + o0] = ov;
}

extern "C" void kernel_launch(void* const* d_in, const int* in_sizes, int n_in,
                              void* d_out, int out_size, void* d_ws, size_t ws_size,
                              hipStream_t stream) {
    const float* nf     = (const float*)d_in[0];
    const float* ef     = (const float*)d_in[1];
    const int*   src    = (const int*)d_in[2];
    const int*   dst    = (const int*)d_in[3];
    const float* W_em1  = (const float*)d_in[4];
    const float* b_em1  = (const float*)d_in[5];
    const float* W_em2  = (const float*)d_in[6];
    const float* b_em2  = (const float*)d_in[7];
    const float* W_np   = (const float*)d_in[8];
    const float* b_np   = (const float*)d_in[9];
    const float* W_fc   = (const float*)d_in[10];
    const float* attn_l = (const float*)d_in[11];
    const float* attn_r = (const float*)d_in[12];
    const float* g_bias = (const float*)d_in[13];
    const float* ln_g   = (const float*)d_in[14];
    const float* ln_b   = (const float*)d_in[15];

    const int N = in_sizes[0] / IN_FEAT;
    const int E = in_sizes[2];

    float* ws = (float*)d_ws;
    size_t off_w = 0;
    auto alloc = [&](size_t nelem) {
        float* p = ws + off_w;
        off_w += (nelem + 63) & ~(size_t)63;   // 256B-align
        return p;
    };
    float* nd    = alloc((size_t)N * 8);       // {outdeg, e0, e1, e2, indeg, pad, pad, pad}
    short* WBh   = (short*)alloc(128 * 128 / 2);   // fragment-ordered bf16 hi
    short* WBl   = (short*)alloc(128 * 128 / 2);   // lo
    float* bvec  = alloc(128);
    unsigned short* h16 = (unsigned short*)alloc((size_t)N * 64);   // N*128 bf16
    float* el    = alloc((size_t)N * 4);
    float* er    = alloc((size_t)N * 4);
    int*   erank  = (int*)alloc(E);
    int*   eoff   = (int*)alloc(N + 1);
    int*   ssrc   = (int*)alloc(E);
    int*   excl   = (int*)alloc(N);
    int*   bsum   = (int*)alloc(1024);

    const int nb = (N + 1023) / 1024;

    wcomb_kernel<<<128, 128, 0, stream>>>(W_np, W_fc, b_np, WBh, WBl, bvec,
                                          (float4*)nd, N * 2);
    edge_scatter_kernel<<<((size_t)E * 8 + 255) / 256, 256, 0, stream>>>(
        ef, src, dst, W_em1, b_em1, W_em2, b_em2, nd, erank, E);
    scan1_kernel<<<nb, 1024, 0, stream>>>(nd, excl, bsum, N);
    scan3_kernel<<<nb, 1024, 0, stream>>>(excl, bsum, eoff, N, E);
    binh_kernel<<<(N + 63) / 64, 256, 0, stream>>>(src, dst, eoff, erank, ssrc, E,
                                                   nf, WBh, WBl, bvec, W_fc, nd,
                                                   attn_l, attn_r, h16, el, er, N);
    gather_kernel<<<((size_t)N * 32 + 255) / 256, 256, 0, stream>>>(eoff, ssrc, el, er, h16, nf,
                                                                    g_bias, ln_g, ln_b,
                                                                    (float*)d_out, N);
}